// Round 4
// baseline (381.308 us; speedup 1.0000x reference)
//
#include <hip/hip_runtime.h>
#include <hip/hip_bf16.h>
#include <hip/hip_cooperative_groups.h>
#include <stdint.h>

namespace cg = cooperative_groups;

#define HW      16384
#define W_      128
#define NA      9
#define BS      8
#define K_TOP   100
#define NDET    800
#define MPAD    832
#define C_FEAT  256
#define FC1_IN  2304
#define FC1_OUT 1024

// output offsets (floats)
#define O_HM    0
#define O_WH1   1179648
#define O_OFF1  1182848
#define O_S1CLS 1184448
#define O_WH2   1185248
#define O_OFF2  1188448
#define O_CLS   1190048
#define O_SWH   1198048
#define O_INDS  1201248
#define O_VAL   1202048

#define NBIN     1024
#define CAND_MAX 512

typedef __attribute__((ext_vector_type(8))) short short8v;
typedef __attribute__((ext_vector_type(4))) float f32x4;

__device__ __forceinline__ void gload16(const void* g, void* l) {
    __builtin_amdgcn_global_load_lds(
        (const __attribute__((address_space(1))) unsigned int*)g,
        (__attribute__((address_space(3))) unsigned int*)l, 16, 0, 0);
}

__device__ __forceinline__ int binof(float v) {
    return max(0, min(NBIN - 1, (int)(v * (float)NBIN)));
}

struct CoopArgs {
    const float* hm; const float* feat; const float* wh; const float* offset;
    const float* w_fc1; const float* w_cls; const float* w_wh;
    float* out; unsigned int* histp; unsigned int* cnt;
    unsigned long long* cand; float* boxes;
    __hip_bfloat16* wt; float* wT14; __hip_bfloat16* roi;
};

// ============ cooperative mega-kernel: topk + prep + roi ============
// grid = 256 blocks (8 batches x 32), 256 threads
__global__ __launch_bounds__(256) void coop_kernel(CoopArgs a) {
    __shared__ float4 slice[1152];                 // this block's hm slice (18 KB)
    __shared__ unsigned int lhist[NBIN];           // local hist, reused as summed hist
    __shared__ float wtt[64][65];                  // W-transpose tile
    __shared__ unsigned long long cd[CAND_MAX];    // sort buffer (phase 2)
    __shared__ int s_T;

    cg::grid_group grid = cg::this_grid();
    const int bid = blockIdx.x, tid = threadIdx.x;
    const int batch = bid >> 5, sub = bid & 31;

    // ---------------- phase 0: hist + hm passthrough + weight prep ----------------
    for (int i = tid; i < NBIN; i += 256) lhist[i] = 0u;
    if (bid < BS && tid == 0) a.cnt[bid] = 0u;     // zero cnt (ordered by grid.sync)
    __syncthreads();

    {
        const float4* src = (const float4*)(a.hm + (size_t)batch * NA * HW) + sub * 1152;
        float4*       dst = (float4*)(a.out + O_HM + (size_t)batch * NA * HW) + sub * 1152;
        for (int i = tid; i < 1152; i += 256) {
            float4 v = src[i];
            dst[i] = v;
            slice[i] = v;
            atomicAdd(&lhist[binof(v.x)], 1u);
            atomicAdd(&lhist[binof(v.y)], 1u);
            atomicAdd(&lhist[binof(v.z)], 1u);
            atomicAdd(&lhist[binof(v.w)], 1u);
        }
        __syncthreads();
        for (int i = tid; i < NBIN; i += 256) a.histp[bid * NBIN + i] = lhist[i];
    }

    // W transpose+convert: 576 64x64 tiles over 256 blocks
    {
        const int c = tid & 63, r = tid >> 6;
        for (int t = bid; t < 576; t += 256) {
            int bk = (t % 36) * 64, bn = (t / 36) * 64;
            for (int k = r; k < 64; k += 4)
                wtt[k][c] = a.w_fc1[(size_t)(bk + k) * FC1_OUT + bn + c];
            __syncthreads();
            for (int nn = r; nn < 64; nn += 4)
                a.wt[(size_t)(bn + nn) * FC1_IN + bk + c] = __float2bfloat16(wtt[c][nn]);
            __syncthreads();
        }
    }
    // fc2 head-weight transpose pack: 14336 elems, blocks 0..55
    if (bid < 56) {
        int idx = bid * 256 + tid;
        int j = idx >> 10, k = idx & 1023;
        a.wT14[idx] = (j < 10) ? a.w_cls[k * 10 + j] : a.w_wh[k * 4 + (j - 10)];
    }

    grid.sync();

    // ---------------- phase 1: threshold + collect (from LDS slice) ----------------
    for (int i = tid; i < NBIN; i += 256) {
        unsigned int s = 0;
        #pragma unroll 8
        for (int sb = 0; sb < 32; ++sb) s += a.histp[(size_t)(batch * 32 + sb) * NBIN + i];
        lhist[i] = s;
    }
    __syncthreads();
    if (tid < 64) {
        int lane = tid;
        unsigned int s = 0;
        #pragma unroll
        for (int i = 0; i < 16; ++i) s += lhist[lane * 16 + i];
        unsigned int suf = s;
        #pragma unroll
        for (int off = 1; off < 64; off <<= 1) {
            unsigned int o = __shfl_down(suf, off);
            if (lane + off < 64) suf += o;
        }
        unsigned long long mask = __ballot(suf >= K_TOP);
        int L = 63 - __clzll(mask);
        unsigned int below = __shfl(suf, L + 1);
        if (L == 63) below = 0;
        if (lane == L) {
            unsigned int acc = below;
            int T = 16 * L;
            for (int i = 15; i >= 0; --i) {
                acc += lhist[16 * L + i];
                if (acc >= K_TOP) { T = 16 * L + i; break; }
            }
            s_T = T;
        }
    }
    __syncthreads();
    {
        const int T = s_T;
        for (int i = tid; i < 1152; i += 256) {
            float4 v4 = slice[i];
            float vv[4] = {v4.x, v4.y, v4.z, v4.w};
            #pragma unroll
            for (int e = 0; e < 4; ++e) {
                if (binof(vv[e]) >= T) {
                    unsigned int p = atomicAdd(&a.cnt[batch], 1u);
                    if (p < CAND_MAX) {
                        int idx = (sub * 1152 + i) * 4 + e;
                        int an = idx >> 14;
                        int pp = idx & (HW - 1);
                        unsigned int flat_i = (unsigned int)(pp * NA + an);
                        a.cand[batch * CAND_MAX + p] =
                            ((unsigned long long)__float_as_uint(vv[e]) << 32)
                            | (unsigned long long)(0xFFFFFFFFu - flat_i);
                    }
                }
            }
        }
    }

    grid.sync();

    // ---------------- phase 2: sort + emit topk outputs + gather + boxes ----------------
    if (bid < BS) {
        const int b = bid;
        unsigned int c = a.cnt[b]; if (c > CAND_MAX) c = CAND_MAX;
        cd[tid]       = (tid < (int)c)       ? a.cand[b * CAND_MAX + tid]       : 0ull;
        cd[tid + 256] = (tid + 256 < (int)c) ? a.cand[b * CAND_MAX + tid + 256] : 0ull;
        __syncthreads();
        for (int k = 2; k <= CAND_MAX; k <<= 1) {
            for (int j = k >> 1; j > 0; j >>= 1) {
                int i   = ((tid & ~(j - 1)) << 1) | (tid & (j - 1));
                int ixj = i | j;
                unsigned long long x = cd[i], y = cd[ixj];
                bool up = ((i & k) == 0);
                if (up ? (x < y) : (x > y)) { cd[i] = y; cd[ixj] = x; }
                __syncthreads();
            }
        }
        if (tid < K_TOP) {
            unsigned long long key = cd[tid];
            float v = __uint_as_float((unsigned int)(key >> 32));
            unsigned int flat_i = 0xFFFFFFFFu - (unsigned int)(key & 0xFFFFFFFFull);
            int an = (int)(flat_i % NA);
            int p  = (int)(flat_i / NA);
            int inds = p + b * HW;
            int o = b * K_TOP + tid;
            a.out[O_VAL + o]   = v;
            a.out[O_S1CLS + o] = (float)an;
            a.out[O_INDS + o]  = (float)inds;
            // reference quirk: select_tensor row index omits the anchor term ->
            // always the batch-0 slab with p2=inds/9, a2=inds%9
            int p2 = inds / NA;
            int a2 = inds - p2 * NA;
            float w0 = a.wh[(size_t)(a2 * 4 + 0) * HW + p2];
            float w1 = a.wh[(size_t)(a2 * 4 + 1) * HW + p2];
            float w2 = a.wh[(size_t)(a2 * 4 + 2) * HW + p2];
            float w3 = a.wh[(size_t)(a2 * 4 + 3) * HW + p2];
            float o0 = a.offset[(size_t)(a2 * 2 + 0) * HW + p2];
            float o1 = a.offset[(size_t)(a2 * 2 + 1) * HW + p2];
            a.out[O_WH1 + o * 4 + 0] = w0; a.out[O_WH1 + o * 4 + 1] = w1;
            a.out[O_WH1 + o * 4 + 2] = w2; a.out[O_WH1 + o * 4 + 3] = w3;
            a.out[O_WH2 + o * 4 + 0] = w0; a.out[O_WH2 + o * 4 + 1] = w1;
            a.out[O_WH2 + o * 4 + 2] = w2; a.out[O_WH2 + o * 4 + 3] = w3;
            a.out[O_OFF1 + o * 2 + 0] = o0; a.out[O_OFF1 + o * 2 + 1] = o1;
            a.out[O_OFF2 + o * 2 + 0] = o0; a.out[O_OFF2 + o * 2 + 1] = o1;
            float xs = (float)(inds % W_) + o0;   // == p % 128
            float ys = (float)(inds / W_) + o1;   // includes b*128 (reference quirk)
            a.boxes[o * 4 + 0] = xs + w0;
            a.boxes[o * 4 + 1] = ys + w1;
            a.boxes[o * 4 + 2] = xs + w2;
            a.boxes[o * 4 + 3] = ys + w3;
        }
    }

    grid.sync();

    // ---------------- phase 3: roi align -> bf16 A [MPAD][2304] ----------------
    for (int n = bid; n < MPAD; n += 256) {
        const int c = tid;   // channel
        __hip_bfloat16* op = a.roi + (size_t)n * FC1_IN + (size_t)c * 9;
        if (n >= NDET) {
            #pragma unroll
            for (int i = 0; i < 9; ++i) op[i] = __float2bfloat16(0.0f);
            continue;
        }
        float x1 = a.boxes[n * 4 + 0], y1 = a.boxes[n * 4 + 1];
        float x2 = a.boxes[n * 4 + 2], y2 = a.boxes[n * 4 + 3];
        int b = n / K_TOP;
        float bw = fmaxf(x2 - x1, 1.0f) / 3.0f;
        float bh = fmaxf(y2 - y1, 1.0f) / 3.0f;
        const float* fb = a.feat + ((size_t)b * C_FEAT + c) * HW;
        #pragma unroll
        for (int gy = 0; gy < 3; ++gy) {
            float ysf = y1 + ((float)gy + 0.5f) * bh;
            #pragma unroll
            for (int gx = 0; gx < 3; ++gx) {
                float xsf = x1 + ((float)gx + 0.5f) * bw;
                bool invalid = (ysf < -1.0f) || (ysf > 128.0f) || (xsf < -1.0f) || (xsf > 128.0f);
                if (invalid) {     // uniform across block -> skip all loads
                    op[gy * 3 + gx] = __float2bfloat16(0.0f);
                    continue;
                }
                float y = fminf(fmaxf(ysf, 0.0f), 127.0f);
                float x = fminf(fmaxf(xsf, 0.0f), 127.0f);
                int y0 = (int)floorf(y);
                int x0 = (int)floorf(x);
                int y1i = min(y0 + 1, 127);
                int x1i = min(x0 + 1, 127);
                float ly = y - (float)y0, lx = x - (float)x0;
                float hy = 1.0f - ly, hx = 1.0f - lx;
                float v00 = fb[y0 * W_ + x0],  v01 = fb[y0 * W_ + x1i];
                float v10 = fb[y1i * W_ + x0], v11 = fb[y1i * W_ + x1i];
                float v = hy * hx * v00 + hy * lx * v01 + ly * hx * v10 + ly * lx * v11;
                op[gy * 3 + gx] = __float2bfloat16(v);
            }
        }
    }
}

// ------- FC1 MFMA, 2-phase double-buffered: (832x2304)@(2304x1024^T)+b, relu ----
__global__ __launch_bounds__(256) void fc1_mfma(const __hip_bfloat16* __restrict__ A,
                                                const __hip_bfloat16* __restrict__ WT,
                                                const float* __restrict__ bias,
                                                float* __restrict__ C) {
    __shared__ char smem[32768];   // 2 x (As [64][128B] swz | Bs [64][128B] swz)
    const int tid = threadIdx.x;
    const int w = tid >> 6, l = tid & 63;
    const int bm0 = blockIdx.x * 64, bn0 = blockIdx.y * 64;
    const char* Ab = (const char*)A;
    const char* Bb = (const char*)WT;

    f32x4 acc[2][2];
    #pragma unroll
    for (int i = 0; i < 2; ++i)
        #pragma unroll
        for (int j = 0; j < 2; ++j) acc[i][j] = (f32x4){0.f, 0.f, 0.f, 0.f};

    const int wr = (w >> 1) * 32, wc = (w & 1) * 32;
    const int lrow = l & 15;
    const int lkb  = (l >> 4) * 16;

    auto STAGE = [&](int k0, int buf) {
        #pragma unroll
        for (int j = 0; j < 4; ++j) {
            int o = j * 4096 + tid * 16;
            const char* src;
            if (o < 8192) {
                int r = o >> 7, bby = o & 127;
                src = Ab + ((size_t)(bm0 + r) * FC1_IN + k0) * 2 + (bby ^ ((r & 7) << 4));
            } else {
                int o2 = o - 8192;
                int r = o2 >> 7, bby = o2 & 127;
                src = Bb + ((size_t)(bn0 + r) * FC1_IN + k0) * 2 + (bby ^ ((r & 7) << 4));
            }
            gload16(src, smem + buf * 16384 + o);
        }
    };

    STAGE(0, 0);
    __syncthreads();
    int cur = 0;
    #pragma unroll 1
    for (int t = 0; t < FC1_IN / 64; ++t) {
        if (t + 1 < FC1_IN / 64) STAGE((t + 1) * 64, cur ^ 1);   // issue-early
        char* sb = smem + cur * 16384;
        #pragma unroll
        for (int kk = 0; kk < 2; ++kk) {
            short8v af[2], bf[2];
            #pragma unroll
            for (int ms = 0; ms < 2; ++ms) {
                int r = wr + ms * 16 + lrow;
                int bby = kk * 64 + lkb;
                af[ms] = *(const short8v*)(sb + r * 128 + (bby ^ ((r & 7) << 4)));
            }
            #pragma unroll
            for (int ns = 0; ns < 2; ++ns) {
                int r = wc + ns * 16 + lrow;
                int bby = kk * 64 + lkb;
                bf[ns] = *(const short8v*)(sb + 8192 + r * 128 + (bby ^ ((r & 7) << 4)));
            }
            #pragma unroll
            for (int ms = 0; ms < 2; ++ms)
                #pragma unroll
                for (int ns = 0; ns < 2; ++ns)
                    acc[ms][ns] = __builtin_amdgcn_mfma_f32_16x16x32_bf16(
                        af[ms], bf[ns], acc[ms][ns], 0, 0, 0);
        }
        __syncthreads();
        cur ^= 1;
    }
    const int col = l & 15, rbase = (l >> 4) * 4;
    #pragma unroll
    for (int ms = 0; ms < 2; ++ms)
        #pragma unroll
        for (int ns = 0; ns < 2; ++ns)
            #pragma unroll
            for (int j = 0; j < 4; ++j) {
                int gm = bm0 + wr + ms * 16 + rbase + j;
                int gn = bn0 + wc + ns * 16 + col;
                if (gm < NDET)
                    C[(size_t)gm * FC1_OUT + gn] = fmaxf(acc[ms][ns][j] + bias[gn], 0.0f);
            }
}

// ---- FC2: heads, weights staged in LDS, 8 rows/block ----
__global__ __launch_bounds__(256) void fc2_kernel(const float* __restrict__ hdn,
                                                  const float* __restrict__ wT14,
                                                  const float* __restrict__ b_cls,
                                                  const float* __restrict__ b_wh,
                                                  float* __restrict__ out) {
    __shared__ float4 wl4[3584];   // 14 x 1024 f32
    __shared__ float bl[14];
    const int tid = threadIdx.x;
    const float4* wg4 = (const float4*)wT14;
    for (int i = tid; i < 3584; i += 256) wl4[i] = wg4[i];
    if (tid < 14) bl[tid] = (tid < 10) ? b_cls[tid] : b_wh[tid - 10];
    __syncthreads();
    const int wv = tid >> 6, lane = tid & 63;
    #pragma unroll
    for (int pass = 0; pass < 2; ++pass) {
        int n = blockIdx.x * 8 + pass * 4 + wv;
        const float4* h4 = (const float4*)(hdn + (size_t)n * FC1_OUT);
        float4 hr[4];
        #pragma unroll
        for (int t = 0; t < 4; ++t) hr[t] = h4[t * 64 + lane];
        for (int j = 0; j < 14; ++j) {
            float s = 0.0f;
            #pragma unroll
            for (int t = 0; t < 4; ++t) {
                float4 w = wl4[j * 256 + t * 64 + lane];
                s += hr[t].x * w.x + hr[t].y * w.y + hr[t].z * w.z + hr[t].w * w.w;
            }
            #pragma unroll
            for (int off = 32; off > 0; off >>= 1) s += __shfl_down(s, off);
            if (lane == 0) {
                if (j < 10) out[O_CLS + n * 10 + j] = s + bl[j];
                else        out[O_SWH + n * 4 + (j - 10)] = s + bl[j];
            }
        }
    }
}

extern "C" void kernel_launch(void* const* d_in, const int* in_sizes, int n_in,
                              void* d_out, int out_size, void* d_ws, size_t ws_size,
                              hipStream_t stream) {
    const float* feat   = (const float*)d_in[0];
    const float* hm     = (const float*)d_in[1];
    const float* wh     = (const float*)d_in[2];
    const float* offset = (const float*)d_in[3];
    const float* w_fc1  = (const float*)d_in[4];
    const float* b_fc1  = (const float*)d_in[5];
    const float* w_cls  = (const float*)d_in[6];
    const float* b_cls  = (const float*)d_in[7];
    const float* w_wh   = (const float*)d_in[8];
    const float* b_wh   = (const float*)d_in[9];
    float* out = (float*)d_out;

    char* ws = (char*)d_ws;
    float*              ws_boxes = (float*)(ws + 0);           // 3200 f
    unsigned int*       ws_cnt   = (unsigned int*)(ws + 16384);
    unsigned long long* ws_cand  = (unsigned long long*)(ws + 32768);    // 8x512 u64
    unsigned int*       ws_histp = (unsigned int*)(ws + 65536);          // 256x1024 u32
    float*              ws_wT14  = (float*)(ws + 1114112);               // 14336 f
    __hip_bfloat16*     ws_wt    = (__hip_bfloat16*)(ws + 1171456);      // 1024x2304
    __hip_bfloat16*     ws_roi   = (__hip_bfloat16*)(ws + 5890048);      // 832x2304
    float*              ws_hdn   = (float*)(ws + 9723904);               // 800x1024

    CoopArgs ca;
    ca.hm = hm; ca.feat = feat; ca.wh = wh; ca.offset = offset;
    ca.w_fc1 = w_fc1; ca.w_cls = w_cls; ca.w_wh = w_wh;
    ca.out = out; ca.histp = ws_histp; ca.cnt = ws_cnt;
    ca.cand = ws_cand; ca.boxes = ws_boxes;
    ca.wt = ws_wt; ca.wT14 = ws_wT14; ca.roi = ws_roi;

    void* kargs[] = { &ca };
    hipLaunchCooperativeKernel((void*)coop_kernel, dim3(256), dim3(256), kargs, 0, stream);

    fc1_mfma  <<<dim3(MPAD / 64, FC1_OUT / 64), 256, 0, stream>>>(ws_roi, ws_wt, b_fc1, ws_hdn);
    fc2_kernel<<<NDET / 8, 256, 0, stream>>>(ws_hdn, ws_wT14, b_cls, b_wh, out);
}